// Round 1
// baseline (35477.835 us; speedup 1.0000x reference)
//
#include <hip/hip_runtime.h>

#define T_STEPS 65536
#define NIN 99
#define HID 64
#define G4 256   // 4*HID gates
#define TS 32    // timesteps per block in the projection kernel
#define PF 8     // prefetch depth (steps) in the recurrence kernel

__device__ __forceinline__ float frcp(float x) { return __builtin_amdgcn_rcpf(x); }
__device__ __forceinline__ float fexp(float x) { return __expf(x); }
__device__ __forceinline__ float sigmoid_f(float x) { return frcp(1.0f + fexp(-x)); }
__device__ __forceinline__ float tanh_f(float x) {
    float ax = fabsf(x);
    float e  = fexp(2.0f * ax);                 // inf for large ax is fine: rcp(inf)=0
    float r  = 1.0f - 2.0f * frcp(e + 1.0f);
    return copysignf(r, x);
}

// ---------------- Kernel 1: xz[t][g] = W_ih[g] . x[t] + b_ih[g] + b_hh[g] ----------------
__global__ __launch_bounds__(256) void xz_kernel(
    const float* __restrict__ x, const float* __restrict__ W_ih,
    const float* __restrict__ b_ih, const float* __restrict__ b_hh,
    float* __restrict__ xz) {
    __shared__ __align__(16) float xs[TS * 100];   // pad row to 100 floats (16B-aligned rows)
    const int g  = threadIdx.x;
    const int t0 = blockIdx.x * TS;

    // stage x tile (contiguous in global) into padded LDS rows
    for (int i = g; i < TS * NIN; i += 256) {
        int tl = i / NIN;
        int j  = i - tl * NIN;
        xs[tl * 100 + j] = x[(size_t)t0 * NIN + i];
    }

    // cache this gate's W_ih row in registers
    float w[NIN];
#pragma unroll
    for (int j = 0; j < NIN; ++j) w[j] = W_ih[g * NIN + j];
    const float bias = b_ih[g] + b_hh[g];
    __syncthreads();

    for (int tl = 0; tl < TS; ++tl) {
        const float* xr = &xs[tl * 100];
        float acc = bias;
#pragma unroll
        for (int j = 0; j < NIN; ++j) acc += w[j] * xr[j];
        xz[(size_t)(t0 + tl) * G4 + g] = acc;
    }
}

// ---------------- Kernel 2: sequential LSTM recurrence + MLP head (single block) ----------------
__global__ __launch_bounds__(256) void lstm_kernel(
    const float* __restrict__ xz, const float* __restrict__ W_hh,
    const float* __restrict__ W1, const float* __restrict__ W2,
    const float* __restrict__ b2, float* __restrict__ out) {
    __shared__ __align__(16) float h_lds[HID];
    __shared__ float gbuf[G4];
    __shared__ float hbuf[32];
    const int g = threadIdx.x;

    // thread g owns gate-row g of W_hh (64 floats in VGPRs)
    float wr[HID];
#pragma unroll
    for (int j = 0; j < HID; ++j) wr[j] = W_hh[g * HID + j];

    float c = 0.0f;                 // cell state lives in wave-0 lanes (g<64)
    if (g < HID) h_lds[g] = 0.0f;
    __syncthreads();

    const float* zp = xz + g;       // lane-coalesced column of xz
    float zcur[PF], znxt[PF];
#pragma unroll
    for (int p = 0; p < PF; ++p) { zcur[p] = zp[(size_t)p * G4]; znxt[p] = 0.0f; }

    const bool is_tanh_gate = (g >= 2 * HID && g < 3 * HID);   // gate 'g' (wave 2)

    for (int tb = 0; tb < T_STEPS; tb += PF) {
        if (tb + PF < T_STEPS) {
#pragma unroll
            for (int p = 0; p < PF; ++p) znxt[p] = zp[(size_t)(tb + PF + p) * G4];
        }
#pragma unroll
        for (int u = 0; u < PF; ++u) {
            // z_g = xz[t][g] + W_hh[g] . h
            float acc = zcur[u];
            const float4* h4 = (const float4*)h_lds;
#pragma unroll
            for (int j4 = 0; j4 < HID / 4; ++j4) {
                float4 hv = h4[j4];
                acc += wr[4 * j4 + 0] * hv.x;
                acc += wr[4 * j4 + 1] * hv.y;
                acc += wr[4 * j4 + 2] * hv.z;
                acc += wr[4 * j4 + 3] * hv.w;
            }
            float a = is_tanh_gate ? tanh_f(acc) : sigmoid_f(acc);
            gbuf[g] = a;
            __syncthreads();
            if (g < HID) {
                float iv = gbuf[g];
                float fv = gbuf[HID + g];
                float gv = gbuf[2 * HID + g];
                float ov = gbuf[3 * HID + g];
                c = fv * c + iv * gv;
                h_lds[g] = ov * tanh_f(c);
            }
            __syncthreads();
        }
#pragma unroll
        for (int p = 0; p < PF; ++p) zcur[p] = znxt[p];
    }

    // head: out = W2 @ relu(W1 @ relu(h_T)) + b2
    if (g < 32) {
        float s = 0.0f;
#pragma unroll
        for (int j = 0; j < HID; ++j) s += W1[g * HID + j] * fmaxf(h_lds[j], 0.0f);
        hbuf[g] = fmaxf(s, 0.0f);
    }
    __syncthreads();
    if (g < 3) {
        float s = b2[g];
#pragma unroll
        for (int j = 0; j < 32; ++j) s += W2[g * 32 + j] * hbuf[j];
        out[g] = s;
    }
}

extern "C" void kernel_launch(void* const* d_in, const int* in_sizes, int n_in,
                              void* d_out, int out_size, void* d_ws, size_t ws_size,
                              hipStream_t stream) {
    const float* x   = (const float*)d_in[0];
    const float* Wih = (const float*)d_in[1];
    const float* Whh = (const float*)d_in[2];
    const float* bih = (const float*)d_in[3];
    const float* bhh = (const float*)d_in[4];
    const float* W1  = (const float*)d_in[5];
    const float* W2  = (const float*)d_in[6];
    const float* b2  = (const float*)d_in[7];
    float* out = (float*)d_out;
    float* xz  = (float*)d_ws;   // T_STEPS * 256 floats = 64 MB

    xz_kernel<<<T_STEPS / TS, 256, 0, stream>>>(x, Wih, bih, bhh, xz);
    lstm_kernel<<<1, 256, 0, stream>>>(xz, Whh, W1, W2, b2, out);
}